// Round 11
// baseline (111.127 us; speedup 1.0000x reference)
//
#include <hip/hip_runtime.h>

#define N_NODES 20000
#define N_EDGES 40000
#define NB 32
#define NS 32
#define NT 64
#define NSC 160                 // scatter blocks, 256 edges each (1 edge/thread)
#define NPREP 180               // 0..159 scatter, 160..179 node bounds, all zero out
#define CAPB 1536               // per-bucket capacity (mean 1250, sigma 35 -> 8 sigma)
#define KBM 8                   // main blocks per segment (8 x 8 waves = 64 chunk slots)
#define NBLKM (NB * KBM)        // 256 main blocks (R8 measured-best geometry)
#define CH 32                   // items per chunk
#define SEG (NS * NT)           // 2048 floats per segment tile
#define STEP200 12.9032258065f  // 200*step, step = 2/31

// ws layout (ints): ecnt[32] | node_base[33] | pad to 72 |
//   sedge: [NB][CAPB] 32-byte coord entries, byte 288, 32B-aligned (1.57 MB)

__device__ __forceinline__ float bcast(float x, int j) {   // force SGPR broadcast
    return __uint_as_float(__builtin_amdgcn_readlane(__float_as_uint(x), j));
}

// Simplified band rule (window < 1 => in-band threshold is ALWAYS the nearest
// integer): s0 = rint(u); add sigma(z(s0)) at s0; add the saturated step (+1)
// from s0+1 onward via the diff column. Algebraically identical to the old
// ceil/floor/2-iter construction in all cases (in-band, upper gap, lower gap),
// same truncation (|z|>6.45 tails ~1.6e-3, passed twice). ~30% fewer VALU ops.
__device__ __forceinline__ void accum_item(float h, float w, int lane,
                                           float* __restrict__ acc,
                                           float* __restrict__ fdiff) {
    const float u = fmaf(h, 15.5f, 15.5f);        // fractional grid index
    const float s0f = rintf(u);                   // v_rndne
    const int s0 = (int)s0f;
    const float e = __expf((u - s0f) * STEP200);  // exp(-z), |arg| <= 6.45
    const float sig = __builtin_amdgcn_rcpf(1.0f + e);
    const int sc = min(max(s0, 0), NS - 1);
    const float val = (s0 == sc) ? w * sig : 0.0f;   // branchless range guard
    atomicAdd(&acc[sc * NT + lane], val);            // ds_add_f32, conflict-free
    const int kec = min(max(s0 + 1, 0), NS);
    atomicAdd(&fdiff[kec * NT + lane], w);           // weighted step start
}

// ---------- kernel 1: zero out + node bounds + compact coordinate scatter ----
__global__ __launch_bounds__(256) void prep_kernel(
        const float* __restrict__ x, const int* __restrict__ ei,
        const int* __restrict__ batch, int* __restrict__ ecnt,
        int* __restrict__ node_base, float4* __restrict__ sedge,
        float* __restrict__ out_zero) {
    const int t = threadIdx.x;
    const int bid = blockIdx.x;
    for (int idx = bid * 256 + t; idx < NB * NS * NT; idx += NPREP * 256)
        out_zero[idx] = 0.0f;

    if (bid < NSC) {                       // scatter: 256 edges, 1 per thread
        __shared__ int h[NB];
        __shared__ int basep[NB];
        if (t < NB) h[t] = 0;
        __syncthreads();
        const int e = bid * 256 + t;
        int b = -1, s = 0, d = 0;
        if (e < N_EDGES) {
            s = ei[e];
            d = ei[N_EDGES + e];
            b = batch[s];
            atomicAdd(&h[b], 1);
        }
        __syncthreads();
        if (t < NB && h[t] > 0) {          // ONE global atomic per (block,bucket)
            basep[t] = atomicAdd(&ecnt[t], h[t]);
            h[t] = 0;
        }
        __syncthreads();
        if (b >= 0) {
            const int p = atomicAdd(&h[b], 1);
            const int g = basep[b] + p;
            if (g < CAPB) {                            // OOB-safe guard
                float4* ep = sedge + (size_t)(b * CAPB + g) * 2;
                ep[0] = make_float4(x[3 * s], x[3 * s + 1], x[3 * s + 2], x[3 * d]);
                ep[1] = make_float4(x[3 * d + 1], x[3 * d + 2], 0.0f, 0.0f);
            }
        }
    } else {                               // node segment bounds (batch sorted)
#pragma unroll
        for (int k = 0; k < 4; k++) {
            const int n = (bid - NSC) * 1024 + k * 256 + t;
            if (n < N_NODES) {
                const int bn = batch[n];
                const int bp = (n == 0) ? -1 : batch[n - 1];
                for (int q = bp + 1; q <= bn; q++) node_base[q] = n;
                if (n == N_NODES - 1)
                    for (int q = bn + 1; q <= NB; q++) node_base[q] = N_NODES;
            }
        }
    }
}

// ---------- kernel 2: main — R8 geometry + simplified accum + atomic out ----
// 256 blocks x 512 thr (measured best: 39.8 us). Readlane-broadcast inner
// loop; per item now ~28 VALU + 2 ds_add (was ~38-40). Epilogue: direct
// atomicAdd into out (R7 proved atomic-vs-store epilogue neutral) — deletes
// the part buffer and the reduce dispatch.
__global__ __launch_bounds__(512) void ect_main_kernel(
        const float* __restrict__ x, const float* __restrict__ v,
        const int* __restrict__ node_base, const int* __restrict__ ecnt,
        const float4* __restrict__ sedge, float* __restrict__ out) {
    __shared__ float acc[SEG];            // 8 KB, bank = lane%32 (free 2-way)
    __shared__ float fdiff[(NS + 1) * NT];// slot NS = dump for "no ones"
    const int t = threadIdx.x;
#pragma unroll
    for (int j = 0; j < 4; j++) acc[t + 512 * j] = 0.0f;
    for (int idx = t; idx < (NS + 1) * NT; idx += 512) fdiff[idx] = 0.0f;
    __syncthreads();

    const int lane = t & 63;
    const int wid = __builtin_amdgcn_readfirstlane(t >> 6);  // 0..7
    const int b = blockIdx.x / KBM;                       // segment
    const int slot = (blockIdx.x % KBM) * 8 + wid;        // 0..63
    const float v0 = v[lane], v1 = v[NT + lane], v2 = v[2 * NT + lane];

    const int nlo = node_base[b], nhi = node_base[b + 1];
    const int nn = nhi - nlo;
    const int ne = min(ecnt[b], CAPB);
    const int cn = (nn + CH - 1) / CH;                    // node chunks (~20)
    const int ce = (ne + CH - 1) / CH;                    // edge chunks (~40)

    for (int c = slot; c < cn + ce; c += KBM * 8) {       // usually <=1 iteration
        if (c < cn) {
            // ---- node chunk, w = +1 ----
            const int base = nlo + c * CH;
            const int cnt = min(nhi - base, CH);
            const int li = base + min(lane & (CH - 1), cnt - 1);   // clamped tail
            const float ax = x[3 * li], ay = x[3 * li + 1], az = x[3 * li + 2];
            for (int j = 0; j < cnt; j++) {
                const float h = fmaf(bcast(ax, j), v0,
                                fmaf(bcast(ay, j), v1, bcast(az, j) * v2));
                accum_item(h, 1.0f, lane, acc, fdiff);
            }
        } else {
            // ---- edge chunk, w = -0.5 ----
            const int base = (c - cn) * CH;
            const int cnt = min(ne - base, CH);
            const int li = b * CAPB + base + min(lane & (CH - 1), cnt - 1);
            const float4* ep = sedge + (size_t)li * 2;
            const float4 A = ep[0], Bv = ep[1];
            for (int j = 0; j < cnt; j++) {
                const float hs = fmaf(bcast(A.x, j), v0,
                                 fmaf(bcast(A.y, j), v1, bcast(A.z, j) * v2));
                const float hd = fmaf(bcast(A.w, j), v0,
                                 fmaf(bcast(Bv.x, j), v1, bcast(Bv.y, j) * v2));
                accum_item(fmaxf(hs, hd), -0.5f, lane, acc, fdiff);
            }
        }
    }
    __syncthreads();

    // integrate weighted ones-counts: acc[s][th] += sum_{k<=s} fdiff[k][th]
    if (t < NT) {
        float run = 0.0f;
#pragma unroll
        for (int s = 0; s < NS; s++) {
            run += fdiff[s * NT + t];
            acc[s * NT + t] += run;
        }
    }
    __syncthreads();

    float* ob = out + b * SEG;
#pragma unroll
    for (int j = 0; j < 4; j++) {
        const int idx = t + 512 * j;
        const float val = acc[idx];
        if (val != 0.0f) atomicAdd(&ob[idx], val);
    }
}

// ---------- launcher: memset cursors + 2 kernel dispatches ----------
extern "C" void kernel_launch(void* const* d_in, const int* in_sizes, int n_in,
                              void* d_out, int out_size, void* d_ws, size_t ws_size,
                              hipStream_t stream) {
    const float* x   = (const float*)d_in[0];   // [N,3]
    const float* v   = (const float*)d_in[1];   // [3,64]
    // d_in[2] = lin: linspace(-1,1,32) hardcoded analytically
    const int*   ei  = (const int*)d_in[3];     // [2,E]
    const int*   bat = (const int*)d_in[4];     // [N], sorted

    float* out = (float*)d_out;                 // [32,32,64]

    int* ecnt      = (int*)d_ws;                // [32] global bucket cursors
    int* node_base = ecnt + NB;                 // [33]
    float4* sedge  = (float4*)((int*)d_ws + 72);// byte 288, 32B-aligned

    hipMemsetAsync(ecnt, 0, NB * sizeof(int), stream);
    prep_kernel<<<NPREP, 256, 0, stream>>>(x, ei, bat, ecnt, node_base, sedge, out);
    ect_main_kernel<<<NBLKM, 512, 0, stream>>>(x, v, node_base, ecnt, sedge, out);
}